// Round 16
// baseline (128.155 us; speedup 1.0000x reference)
//
#include <hip/hip_runtime.h>
#include <math.h>

// Round 27: 2-boundary pipeline — fused hist+scan+scatter (k_front, 2 gbars)
// + streamed k_main. R26 post-mortem: streaming k_main saved only 3us ->
// 7th access-pattern theory dead. Surviving mechanism (explains ALL data):
// every dispatch = implicit L2 invalidate (start) + dirty-L2 writeback (end)
// on 8 non-coherent XCD L2s (~10-15us each). Evidence: R24 cold==warm (L2
// never carries over), R25 looped bodies faster than real dispatches (loops
// skip the flush), R23 L2-residency useless (can't survive a boundary).
// Fix: 4 boundaries -> 2. k_front fuses hist (atomics = already-coherent,
// tickets in REGISTERS, seq[] deleted) | gbar | scan (blocks 0..255, bit-
// exact R26 grouping, Epack sc1) | gbar | scatter (from registers, sc1).
// k_main = R26's verified streamed kernel + last-block final, unchanged.
// All in-kernel patterns verified absmax==0 in R13-R16/R26. Fallback to the
// R26 4-dispatch path if 1024-block co-residency is not provable.

#define NB (1 << 18)             // linear time buckets, lambda = 1
#define BLK 256
#define NC1 32
#define M40 ((1ull << 40) - 1)
#define BAR_FLAG 512
#define BAR_REL  1024

#define STORE_U32_A(p, v) __hip_atomic_store((p), (v), __ATOMIC_RELAXED, __HIP_MEMORY_SCOPE_AGENT)
#define STORE_F32_A(p, v) __hip_atomic_store((p), (v), __ATOMIC_RELAXED, __HIP_MEMORY_SCOPE_AGENT)
#define STORE_U64_A(p, v) __hip_atomic_store((unsigned long long*)(p), (v), __ATOMIC_RELAXED, __HIP_MEMORY_SCOPE_AGENT)
#define LOAD_U32_A(p) __hip_atomic_load((const unsigned*)(p), __ATOMIC_RELAXED, __HIP_MEMORY_SCOPE_AGENT)
#define LOAD_U64_A(p) __hip_atomic_load((const unsigned long long*)(p), __ATOMIC_RELAXED, __HIP_MEMORY_SCOPE_AGENT)
#define LOAD_F32_A(p) __hip_atomic_load((const float*)(p), __ATOMIC_RELAXED, __HIP_MEMORY_SCOPE_AGENT)
#define FADD_U32_A(p, v) __hip_atomic_fetch_add((p), (v), __ATOMIC_RELAXED, __HIP_MEMORY_SCOPE_AGENT)

__device__ __forceinline__ int lin_bucket(float t) {
  int b = (int)(t * 256.0f);     // exact (pow2 scale): strictly monotone
  if (b < 0) b = 0;
  if (b > NB - 1) b = NB - 1;
  return b;
}

// R16-verified parallel-flag grid barrier (requires co-resident grid).
template <int GRID>
__device__ __forceinline__ void gbar(unsigned* bar, unsigned gv) {
  __syncthreads();
  constexpr unsigned BPC = GRID / NC1;
  const int t = threadIdx.x;
  const unsigned grp = blockIdx.x & (NC1 - 1);
  if (blockIdx.x == 0) {
    if (t == 0) {
      unsigned a = FADD_U32_A(bar + grp * 16, 1u);
      if (a == gv * BPC - 1u) STORE_U32_A(bar + BAR_FLAG + grp * 16, gv);
    }
    if (t < NC1) {
      int guard = 0;
      while (LOAD_U32_A(bar + BAR_FLAG + t * 16) < gv) {
        __builtin_amdgcn_s_sleep(1);
        if (++guard > 5000000) break;            // failsafe: never hang
      }
      STORE_U32_A(bar + BAR_REL + t * 16, gv);
    }
    __syncthreads();
  } else {
    if (t == 0) {
      unsigned a = FADD_U32_A(bar + grp * 16, 1u);
      if (a == gv * BPC - 1u) STORE_U32_A(bar + BAR_FLAG + grp * 16, gv);
      int guard = 0;
      while (LOAD_U32_A(bar + BAR_REL + grp * 16) < gv) {
        __builtin_amdgcn_s_sleep(1);
        if (++guard > 5000000) break;
      }
    }
    __syncthreads();
  }
}

// ---------------- fused front: hist | gbar | scan | gbar | scatter --------
template <int GRID>
__global__ void __launch_bounds__(BLK, 4)
k_front(const float2* __restrict__ yt0, const float* __restrict__ yp0,
        const int* __restrict__ Hj, int n, int m,
        unsigned* __restrict__ bar,
        unsigned long long* __restrict__ rec,
        unsigned long long* __restrict__ pub,
        unsigned* __restrict__ bitmap,
        unsigned long long* __restrict__ Epack,
        uint2* __restrict__ skey2, unsigned* __restrict__ sidx) {
  __shared__ unsigned su[BLK];
  __shared__ float    sf[BLK];
  const int t = threadIdx.x, g = blockIdx.x;
  const int gtid = g * BLK + t;

  // ---- P1: hist (ticket stays in register; rec/bitmap atomics = coherent)
  unsigned keyR = 0u, evR = 0u, seqR = 0u; float eR = 0.f;
  if (gtid < n) {
    float2 te = yt0[gtid];
    keyR = __float_as_uint(te.x);
    evR = (te.y != 0.f) ? 0x80000000u : 0u;
    eR = expf(yp0[gtid]);
    int b = lin_bucket(te.x);
    unsigned long long qe = (unsigned long long)(eR * 16777216.0f + 0.5f);
    if (qe > (1ull << 32)) qe = (1ull << 32);   // distribution safety clamp
    unsigned long long ret = atomicAdd(&rec[b], (1ull << 40) | qe);
    seqR = (unsigned)(ret >> 40);
  }
  for (int j = gtid; j < m; j += GRID * BLK) {   // Hj rank bitmap
    int h = Hj[j];
    atomicOr(&bitmap[h >> 5], 1u << (h & 31));
  }
  gbar<GRID>(bar, 1);

  // ---- P2: suffix scan, blocks 0..NB/1024-1, BIT-EXACT R26 grouping ------
  if (g < NB / 1024) {
    unsigned cK[4]; float fK[4];
    unsigned runc = 0u; float runf = 0.f;
    #pragma unroll
    for (int k = 0; k < 4; ++k) {
      int b = NB - 1 - (g * 1024 + t * 4 + k);   // descending buckets
      unsigned long long v = rec[b];             // plain read post-gbar: 1st touch
      cK[k] = (unsigned)(v >> 40);
      fK[k] = (float)((double)(v & M40) * (1.0 / 16777216.0));
      runc += cK[k]; runf += fK[k];
    }
    su[t] = runc; sf[t] = runf;
    __syncthreads();
    for (int off2 = 1; off2 < BLK; off2 <<= 1) { // inclusive Hillis-Steele
      unsigned uc = (t >= off2) ? su[t - off2] : 0u;
      float    uf = (t >= off2) ? sf[t - off2] : 0.f;
      __syncthreads();
      su[t] += uc; sf[t] += uf;
      __syncthreads();
    }
    if (t == BLK - 1)
      STORE_U64_A(&pub[g], (1ull << 63) |
                  ((unsigned long long)(su[t] & 0x7FFFFFFFu) << 32) |
                  (unsigned long long)__float_as_uint(sf[t]));
    unsigned thrC = (t > 0) ? su[t - 1] : 0u;
    float    thrF = (t > 0) ? sf[t - 1] : 0.f;
    __syncthreads();

    unsigned pc = 0u; float pf = 0.f;
    for (int j = t; j < g; j += BLK) {           // decoupled lookback
      unsigned long long v;
      int guard = 0;
      while (!(((v = LOAD_U64_A(&pub[j])) >> 63) & 1ull)) {
        __builtin_amdgcn_s_sleep(1);
        if (++guard > 5000000) break;            // failsafe: never hang
      }
      pc += (unsigned)((v >> 32) & 0x7FFFFFFFu);
      pf += __uint_as_float((unsigned)v);
    }
    su[t] = pc; sf[t] = pf;
    __syncthreads();
    for (int s = BLK / 2; s > 0; s >>= 1) {
      if (t < s) { su[t] += su[t + s]; sf[t] += sf[t + s]; }
      __syncthreads();
    }
    const unsigned baseC = su[0]; const float baseF = sf[0];
    __syncthreads();

    unsigned preC = 0u; float preF = 0.f;
    #pragma unroll
    for (int k = 0; k < 4; ++k) {
      int b = NB - 1 - (g * 1024 + t * 4 + k);
      unsigned sfxC = baseC + thrC + preC;       // S[b] (elems in buckets > b)
      float    sfxF = baseF + thrF + preF;       // crossF[b]
      STORE_U64_A(&Epack[b],
                  ((unsigned long long)__float_as_uint(sfxF) << 32) | sfxC);
      preC += cK[k]; preF += fK[k];
    }
  }
  gbar<GRID>(bar, 2);

  // ---- P3: scatter from registers (sc1 -> coherent point) ----------------
  if (gtid < n) {
    unsigned b = (unsigned)lin_bucket(__uint_as_float(keyR));
    unsigned start = ((const unsigned*)Epack)[2u * b];  // 1st-touch plain read
    unsigned pos = start + seqR;
    if (pos < (unsigned)n) {
      STORE_U64_A(&skey2[pos],
                  ((unsigned long long)__float_as_uint(eR) << 32) | keyR);
      STORE_U32_A(&sidx[pos], (unsigned)gtid | evR);
    }
  }
}

// ---------------- fallback D1-D3 (R26, used only if not co-resident) -----
__global__ void __launch_bounds__(BLK, 4)
k_hist(const float2* __restrict__ yt0, const float* __restrict__ yp0,
       const int* __restrict__ Hj, int n, int m, int tot,
       unsigned long long* __restrict__ rec, unsigned* __restrict__ seq,
       unsigned* __restrict__ bitmap) {
  int i = blockIdx.x * BLK + threadIdx.x;
  if (i < n) {
    float2 te = yt0[i];
    float e = expf(yp0[i]);
    int b = lin_bucket(te.x);
    unsigned long long qe = (unsigned long long)(e * 16777216.0f + 0.5f);
    if (qe > (1ull << 32)) qe = (1ull << 32);
    unsigned long long ret = atomicAdd(&rec[b], (1ull << 40) | qe);
    seq[i] = (unsigned)(ret >> 40);
  }
  for (int j = i; j < m; j += tot) {
    int h = Hj[j];
    atomicOr(&bitmap[h >> 5], 1u << (h & 31));
  }
}

__global__ void __launch_bounds__(BLK, 4)
k_scan(const unsigned long long* __restrict__ rec,
       unsigned long long* __restrict__ pub,
       unsigned long long* __restrict__ Epack) {
  __shared__ unsigned su[BLK];
  __shared__ float    sf[BLK];
  const int t = threadIdx.x, g = blockIdx.x;
  unsigned cK[4]; float fK[4];
  unsigned runc = 0u; float runf = 0.f;
  #pragma unroll
  for (int k = 0; k < 4; ++k) {
    int b = NB - 1 - (g * 1024 + t * 4 + k);
    unsigned long long v = rec[b];
    cK[k] = (unsigned)(v >> 40);
    fK[k] = (float)((double)(v & M40) * (1.0 / 16777216.0));
    runc += cK[k]; runf += fK[k];
  }
  su[t] = runc; sf[t] = runf;
  __syncthreads();
  for (int off2 = 1; off2 < BLK; off2 <<= 1) {
    unsigned uc = (t >= off2) ? su[t - off2] : 0u;
    float    uf = (t >= off2) ? sf[t - off2] : 0.f;
    __syncthreads();
    su[t] += uc; sf[t] += uf;
    __syncthreads();
  }
  if (t == BLK - 1)
    STORE_U64_A(&pub[g], (1ull << 63) |
                ((unsigned long long)(su[t] & 0x7FFFFFFFu) << 32) |
                (unsigned long long)__float_as_uint(sf[t]));
  unsigned thrC = (t > 0) ? su[t - 1] : 0u;
  float    thrF = (t > 0) ? sf[t - 1] : 0.f;
  __syncthreads();
  unsigned pc = 0u; float pf = 0.f;
  for (int j = t; j < g; j += BLK) {
    unsigned long long v;
    int guard = 0;
    while (!(((v = LOAD_U64_A(&pub[j])) >> 63) & 1ull)) {
      __builtin_amdgcn_s_sleep(1);
      if (++guard > 5000000) break;
    }
    pc += (unsigned)((v >> 32) & 0x7FFFFFFFu);
    pf += __uint_as_float((unsigned)v);
  }
  su[t] = pc; sf[t] = pf;
  __syncthreads();
  for (int s = BLK / 2; s > 0; s >>= 1) {
    if (t < s) { su[t] += su[t + s]; sf[t] += sf[t + s]; }
    __syncthreads();
  }
  const unsigned baseC = su[0]; const float baseF = sf[0];
  __syncthreads();
  unsigned preC = 0u; float preF = 0.f;
  #pragma unroll
  for (int k = 0; k < 4; ++k) {
    int b = NB - 1 - (g * 1024 + t * 4 + k);
    unsigned sfxC = baseC + thrC + preC;
    float    sfxF = baseF + thrF + preF;
    Epack[b] = ((unsigned long long)__float_as_uint(sfxF) << 32) | sfxC;
    preC += cK[k]; preF += fK[k];
  }
}

__global__ void __launch_bounds__(BLK, 4)
k_scatter(const float2* __restrict__ yt0, const float* __restrict__ yp0, int n,
          const unsigned* __restrict__ seq,
          const unsigned long long* __restrict__ Epack,
          uint2* __restrict__ skey2, unsigned* __restrict__ sidx) {
  int i = blockIdx.x * BLK + threadIdx.x;
  if (i >= n) return;
  float2 te = yt0[i];
  unsigned key = __float_as_uint(te.x);
  unsigned ev = (te.y != 0.f) ? 0x80000000u : 0u;
  int b = lin_bucket(te.x);
  unsigned start = ((const unsigned*)Epack)[2u * (unsigned)b];
  float e = expf(yp0[i]);
  unsigned pos = start + seq[i];
  if (pos < (unsigned)n) {
    uint2 v; v.x = key; v.y = __float_as_uint(e);
    skey2[pos] = v;
    sidx[pos] = (unsigned)i | ev;
  }
}

// ---------------- D-last: STREAMING main (scattered order) + final -------
__global__ void __launch_bounds__(BLK, 4)
k_main(const float* __restrict__ yp1, const int* __restrict__ Hj,
       const float* __restrict__ lv, int n, int m,
       const unsigned* __restrict__ bitmap,
       const unsigned long long* __restrict__ Epack,
       const uint2* __restrict__ skey2, const unsigned* __restrict__ sidx,
       float* __restrict__ xh, double* __restrict__ accum,
       unsigned* __restrict__ doneCnt, float* __restrict__ out) {
  __shared__ double sd[BLK];
  __shared__ float  wt[4];
  __shared__ int    lastFlag;
  const int t = threadIdx.x;
  int p = blockIdx.x * BLK + t;
  double contrib = 0.0;
  if (p < n) {
    uint2 kv = skey2[p];                          // coalesced stream
    unsigned key = kv.x;
    float e = __uint_as_float(kv.y);
    unsigned sidv = sidx[p];                      // coalesced stream
    unsigned idx = sidv & 0x7FFFFFFFu;
    bool evb = (sidv >> 31) != 0u;
    int b = lin_bucket(__uint_as_float(key));
    unsigned long long ep = Epack[b];             // sequential-ish: L1 hit
    unsigned start = (unsigned)ep;
    float cross = __uint_as_float((unsigned)(ep >> 32));
    unsigned end = (b > 0) ? ((const unsigned*)Epack)[2u * (unsigned)(b - 1)]
                           : (unsigned)n;
    if (end > (unsigned)n) end = (unsigned)n;     // defensive clamps
    if (start > end) start = end;
    float wsum = 0.f;
    unsigned wcnt = 0u;
    if (end - start > 1u) {                       // walk = own neighborhood
      for (unsigned q = start; q < end; ++q) {
        uint2 v = skey2[q];
        if (v.x > key) { wsum += __uint_as_float(v.y); wcnt++; }
        else if (v.x == key && (sidx[q] & 0x7FFFFFFFu) < idx) {
          wsum += __uint_as_float(v.y); wcnt++;
        }
      }
    }
    float denom = cross + wsum + e;
    int rank = (int)(start + wcnt);
    if (evb) contrib = (double)logf(denom / e);
    if ((bitmap[rank >> 5] >> (rank & 31)) & 1u) {   // rank~p: sequential
      int lo = 0, hi = m;
      while (lo < hi) { int mid = (lo + hi) >> 1; if (Hj[mid] < rank) lo = mid + 1; else hi = mid; }
      if (lo < m && Hj[lo] == rank) {
        float xb1 = yp1[idx];                     // rare random gather (~3%)
        for (int j = lo; j < m && Hj[j] == rank; ++j) STORE_F32_A(&xh[j], xb1);
      }
    }
  }
  sd[t] = contrib;
  __syncthreads();
  for (int s = 128; s > 0; s >>= 1) { if (t < s) sd[t] += sd[t + s]; __syncthreads(); }
  if (t == 0) {
    double old = atomicAdd(accum, sd[0]);
    unsigned long long ob = __double_as_longlong(old);
    asm volatile("" :: "v"(ob));                  // force accum RMW completion
    unsigned r = FADD_U32_A(doneCnt, 1u);
    lastFlag = (r == gridDim.x - 1u) ? 1 : 0;
  }
  __syncthreads();
  if (lastFlag == 0) return;

  {                                              // P6 (last block only)
    int lane = t & 63;
    int w = t >> 6;
    double acc = 0.0;
    float carry = 0.f;
    int passes = (m + 2047) / 2048;               // 4 for m=8192
    for (int pss = passes - 1; pss >= 0; --pss) {
      int base = pss * 2048 + t * 8;
      float x[8], eb[8];
      float c = 0.f;
      #pragma unroll
      for (int k = 0; k < 8; ++k) {
        int j = base + k;
        x[k] = (j < m) ? LOAD_F32_A(&xh[j]) : 0.f;
        eb[k] = (j < m) ? expf(-x[k]) : 0.f;
        c += eb[k];
      }
      float s = c;
      #pragma unroll
      for (int d = 1; d < 64; d <<= 1) {
        float o = __shfl_down(s, d, 64);
        if (lane + d < 64) s += o;
      }
      float wtot = __shfl(s, 0, 64);
      if (lane == 0) wt[w] = wtot;
      __syncthreads();
      float after = 0.f, ptot = 0.f;
      #pragma unroll
      for (int w2 = 0; w2 < 4; ++w2) { ptot += wt[w2]; if (w2 > w) after += wt[w2]; }
      float S = (s - c) + after + carry;
      #pragma unroll
      for (int k = 7; k >= 0; --k) {
        int j = base + k;
        S += eb[k];
        if (j < m) acc += (double)(expf(x[k]) * S);
      }
      __syncthreads();
      carry += ptot;
    }
    sd[t] = acc;
    __syncthreads();
    for (int s2 = 128; s2 > 0; s2 >>= 1) { if (t < s2) sd[t] += sd[t + s2]; __syncthreads(); }
    if (t == 0) {
      double T = (double)m * (double)(m + 1) * 0.5;
      double cost2 = T - sd[0];
      float lv0 = lv[0], lv1 = lv[1];
      float prec1 = fminf(expf(-lv1), 1.0f);
      double av = __longlong_as_double((long long)LOAD_U64_A(accum));
      double loss = av + (double)n * (double)lv0 + (double)prec1 * cost2 + (double)lv1;
      out[0] = (float)loss;
    }
  }
}

extern "C" void kernel_launch(void* const* d_in, const int* in_sizes, int n_in,
                              void* d_out, int out_size, void* d_ws, size_t ws_size,
                              hipStream_t stream) {
  (void)n_in; (void)out_size;
  const float2* yt0 = (const float2*)d_in[0];
  const float*  yp0 = (const float*)d_in[2];
  const float*  yp1 = (const float*)d_in[3];
  const int*    Hj  = (const int*)d_in[4];
  const float*  lv  = (const float*)d_in[5];
  int n = in_sizes[0] / 2;   // y_true0 is [N,2]
  int m = in_sizes[4];

  char* ws = (char*)d_ws;
  size_t off = 0;
  auto alloc = [&](size_t bytes) -> void* {
    void* p = ws + off;
    off += (bytes + 255) & ~(size_t)255;
    return p;
  };
  double*   accum   = (double*)alloc(128);                         // zeroed
  unsigned* doneCnt = (unsigned*)alloc(128);                       // zeroed
  unsigned* bar     = (unsigned*)alloc(8192);                      // zeroed
  size_t nbm = ((size_t)(n + 31) / 32) * 4;                        // 32 KB
  unsigned* bitmap  = (unsigned*)alloc(nbm);                       // zeroed
  unsigned long long* pub = (unsigned long long*)alloc((NB / 1024) * 8); // zeroed
  unsigned long long* rec = (unsigned long long*)alloc((size_t)NB * 8);  // 2MB zeroed
  size_t zbytes = off;                     // everything above must start zero
  unsigned long long* Epack = (unsigned long long*)alloc((size_t)NB * 8); // 2MB
  unsigned* seq   = (unsigned*)alloc((size_t)n * 4);               // fallback only
  uint2*    skey2 = (uint2*)alloc((size_t)n * 8);                  // 2MB
  unsigned* sidx  = (unsigned*)alloc((size_t)n * 4);               // 1MB
  float*    xh    = (float*)alloc((size_t)m * 4);
  if (off > ws_size) return;

  hipMemsetAsync(ws, 0, zbytes, stream);

  int gN = (n + BLK - 1) / BLK;              // 1024 for n=262144
  int tot = gN * BLK;
  int gS = NB / 1024;                        // 256 scan blocks

  // fused path requires exactly 1024 co-resident blocks
  static int fusedOK = 0;
  if (fusedOK == 0) {
    int nb = 0;
    hipError_t e1 = hipOccupancyMaxActiveBlocksPerMultiprocessor(&nb, k_front<1024>, BLK, 0);
    int dev = 0; hipGetDevice(&dev);
    hipDeviceProp_t prop;
    hipError_t e2 = hipGetDeviceProperties(&prop, dev);
    fusedOK = (e1 == hipSuccess && e2 == hipSuccess &&
               nb * prop.multiProcessorCount >= 1024) ? 1 : -1;
  }

  if (gN == 1024 && fusedOK == 1) {
    k_front<1024><<<dim3(1024), dim3(BLK), 0, stream>>>(
        yt0, yp0, Hj, n, m, bar, rec, pub, bitmap, Epack, skey2, sidx);
  } else {
    k_hist<<<dim3(gN), dim3(BLK), 0, stream>>>(yt0, yp0, Hj, n, m, tot,
                                               rec, seq, bitmap);
    k_scan<<<dim3(gS), dim3(BLK), 0, stream>>>(rec, pub, Epack);
    k_scatter<<<dim3(gN), dim3(BLK), 0, stream>>>(yt0, yp0, n, seq, Epack,
                                                  skey2, sidx);
  }
  k_main<<<dim3(gN), dim3(BLK), 0, stream>>>(yp1, Hj, lv, n, m,
                                             bitmap, Epack, skey2, sidx,
                                             xh, accum, doneCnt,
                                             (float*)d_out);
}

// Round 17
// 124.247 us; speedup vs baseline: 1.0315x; 1.0315x over previous
//
#include <hip/hip_runtime.h>
#include <math.h>

// Round 28 (TERMINAL REVERT): best-measured variant = R26's 4-dispatch
// streamed pipeline (125.8us, absmax 0.0). R27's 2-boundary fusion measured
// equal-or-worse (128.2): gbar cost == boundary cost (~8 vs ~4.3x2 us).
// Structural ceiling (all measured): F~64us harness (poison fill 42us +
// resets); pipeline ~61us = 47.6us loop-isolated body time (latency-bound,
// compulsory-cold L2 per dispatch on 8 non-coherent XCDs; R24 cold==warm)
// + ~17us sync invariant under dispatch<->gbar exchange (R16). Nine
// structural rewrites each moved <=3us; last six rounds span 125.8-128.5.
// Remaining costs are operation-class: 262k device-scope returning atomics
// (rank tickets), data-dependent permutation, XCD boundary cache semantics.
// Pipeline: memset | k_hist | k_scan(lookback) | k_scatter | k_main(+final).

#define NB (1 << 18)             // linear time buckets, lambda = 1
#define BLK 256
#define M40 ((1ull << 40) - 1)

#define STORE_F32_A(p, v) __hip_atomic_store((p), (v), __ATOMIC_RELAXED, __HIP_MEMORY_SCOPE_AGENT)
#define STORE_U64_A(p, v) __hip_atomic_store((unsigned long long*)(p), (v), __ATOMIC_RELAXED, __HIP_MEMORY_SCOPE_AGENT)
#define LOAD_U64_A(p) __hip_atomic_load((const unsigned long long*)(p), __ATOMIC_RELAXED, __HIP_MEMORY_SCOPE_AGENT)
#define LOAD_F32_A(p) __hip_atomic_load((const float*)(p), __ATOMIC_RELAXED, __HIP_MEMORY_SCOPE_AGENT)
#define FADD_U32_A(p, v) __hip_atomic_fetch_add((p), (v), __ATOMIC_RELAXED, __HIP_MEMORY_SCOPE_AGENT)

__device__ __forceinline__ int lin_bucket(float t) {
  int b = (int)(t * 256.0f);     // exact (pow2 scale): strictly monotone
  if (b < 0) b = 0;
  if (b > NB - 1) b = NB - 1;
  return b;
}

// ---------------- D1: histogram + ticket + bitmap ----------------
__global__ void __launch_bounds__(BLK, 4)
k_hist(const float2* __restrict__ yt0, const float* __restrict__ yp0,
       const int* __restrict__ Hj, int n, int m, int tot,
       unsigned long long* __restrict__ rec, unsigned* __restrict__ seq,
       unsigned* __restrict__ bitmap) {
  int i = blockIdx.x * BLK + threadIdx.x;
  if (i < n) {
    float2 te = yt0[i];
    float e = expf(yp0[i]);
    int b = lin_bucket(te.x);
    unsigned long long qe = (unsigned long long)(e * 16777216.0f + 0.5f);
    if (qe > (1ull << 32)) qe = (1ull << 32);   // distribution safety clamp
    unsigned long long ret = atomicAdd(&rec[b], (1ull << 40) | qe);
    seq[i] = (unsigned)(ret >> 40);
  }
  for (int j = i; j < m; j += tot) {             // Hj rank bitmap
    int h = Hj[j];
    atomicOr(&bitmap[h >> 5], 1u << (h & 31));
  }
}

// ---------------- D2: single-pass suffix scan (decoupled lookback) -------
__global__ void __launch_bounds__(BLK, 4)
k_scan(const unsigned long long* __restrict__ rec,
       unsigned long long* __restrict__ pub,
       unsigned long long* __restrict__ Epack) {
  __shared__ unsigned su[BLK];
  __shared__ float    sf[BLK];
  const int t = threadIdx.x, g = blockIdx.x;

  unsigned cK[4]; float fK[4];
  unsigned runc = 0u; float runf = 0.f;
  #pragma unroll
  for (int k = 0; k < 4; ++k) {
    int b = NB - 1 - (g * 1024 + t * 4 + k);
    unsigned long long v = rec[b];
    cK[k] = (unsigned)(v >> 40);
    fK[k] = (float)((double)(v & M40) * (1.0 / 16777216.0));
    runc += cK[k]; runf += fK[k];
  }
  su[t] = runc; sf[t] = runf;
  __syncthreads();
  for (int off2 = 1; off2 < BLK; off2 <<= 1) {   // inclusive Hillis-Steele
    unsigned uc = (t >= off2) ? su[t - off2] : 0u;
    float    uf = (t >= off2) ? sf[t - off2] : 0.f;
    __syncthreads();
    su[t] += uc; sf[t] += uf;
    __syncthreads();
  }
  if (t == BLK - 1)
    STORE_U64_A(&pub[g], (1ull << 63) |
                ((unsigned long long)(su[t] & 0x7FFFFFFFu) << 32) |
                (unsigned long long)__float_as_uint(sf[t]));
  unsigned thrC = (t > 0) ? su[t - 1] : 0u;
  float    thrF = (t > 0) ? sf[t - 1] : 0.f;
  __syncthreads();

  unsigned pc = 0u; float pf = 0.f;
  for (int j = t; j < g; j += BLK) {
    unsigned long long v;
    int guard = 0;
    while (!(((v = LOAD_U64_A(&pub[j])) >> 63) & 1ull)) {
      __builtin_amdgcn_s_sleep(1);
      if (++guard > 5000000) break;              // failsafe: never hang
    }
    pc += (unsigned)((v >> 32) & 0x7FFFFFFFu);
    pf += __uint_as_float((unsigned)v);
  }
  su[t] = pc; sf[t] = pf;
  __syncthreads();
  for (int s = BLK / 2; s > 0; s >>= 1) {
    if (t < s) { su[t] += su[t + s]; sf[t] += sf[t + s]; }
    __syncthreads();
  }
  const unsigned baseC = su[0]; const float baseF = sf[0];
  __syncthreads();

  unsigned preC = 0u; float preF = 0.f;
  #pragma unroll
  for (int k = 0; k < 4; ++k) {
    int b = NB - 1 - (g * 1024 + t * 4 + k);
    unsigned sfxC = baseC + thrC + preC;          // S[b] (elems in buckets > b)
    float    sfxF = baseF + thrF + preF;          // crossF[b]
    Epack[b] = ((unsigned long long)__float_as_uint(sfxF) << 32) | sfxC;
    preC += cK[k]; preF += fK[k];
  }
}

// ---------------- D3: scatter ALL elements ----------------
__global__ void __launch_bounds__(BLK, 4)
k_scatter(const float2* __restrict__ yt0, const float* __restrict__ yp0, int n,
          const unsigned* __restrict__ seq,
          const unsigned long long* __restrict__ Epack,
          uint2* __restrict__ skey2, unsigned* __restrict__ sidx) {
  int i = blockIdx.x * BLK + threadIdx.x;
  if (i >= n) return;
  float2 te = yt0[i];
  unsigned key = __float_as_uint(te.x);
  unsigned ev = (te.y != 0.f) ? 0x80000000u : 0u;
  int b = lin_bucket(te.x);
  unsigned start = ((const unsigned*)Epack)[2u * (unsigned)b];  // only random read
  float e = expf(yp0[i]);                         // bitwise == k_hist's e
  unsigned pos = start + seq[i];
  uint2 v; v.x = key; v.y = __float_as_uint(e);
  skey2[pos] = v;                                 // random write, 3MB L2-merged
  sidx[pos] = (unsigned)i | ev;
}

// ---------------- D4: STREAMING main (scattered order) + final -----------
__global__ void __launch_bounds__(BLK, 4)
k_main(const float* __restrict__ yp1, const int* __restrict__ Hj,
       const float* __restrict__ lv, int n, int m,
       const unsigned* __restrict__ bitmap,
       const unsigned long long* __restrict__ Epack,
       const uint2* __restrict__ skey2, const unsigned* __restrict__ sidx,
       float* __restrict__ xh, double* __restrict__ accum,
       unsigned* __restrict__ doneCnt, float* __restrict__ out) {
  __shared__ double sd[BLK];
  __shared__ float  wt[4];
  __shared__ int    lastFlag;
  const int t = threadIdx.x;
  int p = blockIdx.x * BLK + t;
  double contrib = 0.0;
  if (p < n) {
    uint2 kv = skey2[p];                          // coalesced stream
    unsigned key = kv.x;
    float e = __uint_as_float(kv.y);
    unsigned sidv = sidx[p];                      // coalesced stream
    unsigned idx = sidv & 0x7FFFFFFFu;
    bool evb = (sidv >> 31) != 0u;
    int b = lin_bucket(__uint_as_float(key));
    unsigned long long ep = Epack[b];             // sequential-ish: L1 hit
    unsigned start = (unsigned)ep;
    float cross = __uint_as_float((unsigned)(ep >> 32));
    unsigned end = (b > 0) ? ((const unsigned*)Epack)[2u * (unsigned)(b - 1)]
                           : (unsigned)n;
    if (end > (unsigned)n) end = (unsigned)n;     // defensive clamps
    if (start > end) start = end;
    float wsum = 0.f;
    unsigned wcnt = 0u;
    if (end - start > 1u) {                       // walk = own neighborhood
      for (unsigned q = start; q < end; ++q) {
        uint2 v = skey2[q];
        if (v.x > key) { wsum += __uint_as_float(v.y); wcnt++; }
        else if (v.x == key && (sidx[q] & 0x7FFFFFFFu) < idx) {
          wsum += __uint_as_float(v.y); wcnt++;
        }
      }
    }
    float denom = cross + wsum + e;
    int rank = (int)(start + wcnt);
    if (evb) contrib = (double)logf(denom / e);
    if ((bitmap[rank >> 5] >> (rank & 31)) & 1u) {   // rank~p: sequential
      int lo = 0, hi = m;
      while (lo < hi) { int mid = (lo + hi) >> 1; if (Hj[mid] < rank) lo = mid + 1; else hi = mid; }
      if (lo < m && Hj[lo] == rank) {
        float xb1 = yp1[idx];                     // rare random gather (~3%)
        for (int j = lo; j < m && Hj[j] == rank; ++j) STORE_F32_A(&xh[j], xb1);
      }
    }
  }
  sd[t] = contrib;
  __syncthreads();
  for (int s = 128; s > 0; s >>= 1) { if (t < s) sd[t] += sd[t + s]; __syncthreads(); }
  // last __syncthreads drained every wave's stores (incl. sc1 xh writes)
  if (t == 0) {
    double old = atomicAdd(accum, sd[0]);
    unsigned long long ob = __double_as_longlong(old);
    asm volatile("" :: "v"(ob));                  // force accum RMW completion
    unsigned r = FADD_U32_A(doneCnt, 1u);
    lastFlag = (r == gridDim.x - 1u) ? 1 : 0;
  }
  __syncthreads();
  if (lastFlag == 0) return;

  // ---- P6 (last block only): cost2 + combine ----
  {
    int lane = t & 63;
    int w = t >> 6;
    double acc = 0.0;
    float carry = 0.f;
    int passes = (m + 2047) / 2048;               // 4 for m=8192
    for (int pss = passes - 1; pss >= 0; --pss) {
      int base = pss * 2048 + t * 8;
      float x[8], eb[8];
      float c = 0.f;
      #pragma unroll
      for (int k = 0; k < 8; ++k) {
        int j = base + k;
        x[k] = (j < m) ? LOAD_F32_A(&xh[j]) : 0.f;
        eb[k] = (j < m) ? expf(-x[k]) : 0.f;
        c += eb[k];
      }
      float s = c;
      #pragma unroll
      for (int d = 1; d < 64; d <<= 1) {
        float o = __shfl_down(s, d, 64);
        if (lane + d < 64) s += o;
      }
      float wtot = __shfl(s, 0, 64);
      if (lane == 0) wt[w] = wtot;
      __syncthreads();
      float after = 0.f, ptot = 0.f;
      #pragma unroll
      for (int w2 = 0; w2 < 4; ++w2) { ptot += wt[w2]; if (w2 > w) after += wt[w2]; }
      float S = (s - c) + after + carry;
      #pragma unroll
      for (int k = 7; k >= 0; --k) {
        int j = base + k;
        S += eb[k];
        if (j < m) acc += (double)(expf(x[k]) * S);
      }
      __syncthreads();
      carry += ptot;
    }
    sd[t] = acc;
    __syncthreads();
    for (int s2 = 128; s2 > 0; s2 >>= 1) { if (t < s2) sd[t] += sd[t + s2]; __syncthreads(); }
    if (t == 0) {
      double T = (double)m * (double)(m + 1) * 0.5;
      double cost2 = T - sd[0];
      float lv0 = lv[0], lv1 = lv[1];
      float prec1 = fminf(expf(-lv1), 1.0f);
      double av = __longlong_as_double((long long)LOAD_U64_A(accum));
      double loss = av + (double)n * (double)lv0 + (double)prec1 * cost2 + (double)lv1;
      out[0] = (float)loss;
    }
  }
}

extern "C" void kernel_launch(void* const* d_in, const int* in_sizes, int n_in,
                              void* d_out, int out_size, void* d_ws, size_t ws_size,
                              hipStream_t stream) {
  (void)n_in; (void)out_size;
  const float2* yt0 = (const float2*)d_in[0];
  const float*  yp0 = (const float*)d_in[2];
  const float*  yp1 = (const float*)d_in[3];
  const int*    Hj  = (const int*)d_in[4];
  const float*  lv  = (const float*)d_in[5];
  int n = in_sizes[0] / 2;   // y_true0 is [N,2]
  int m = in_sizes[4];

  char* ws = (char*)d_ws;
  size_t off = 0;
  auto alloc = [&](size_t bytes) -> void* {
    void* p = ws + off;
    off += (bytes + 255) & ~(size_t)255;
    return p;
  };
  double*   accum   = (double*)alloc(128);                         // zeroed
  unsigned* doneCnt = (unsigned*)alloc(128);                       // zeroed
  size_t nbm = ((size_t)(n + 31) / 32) * 4;                        // 32 KB
  unsigned* bitmap  = (unsigned*)alloc(nbm);                       // zeroed
  unsigned long long* pub = (unsigned long long*)alloc((NB / 1024) * 8); // zeroed
  unsigned long long* rec = (unsigned long long*)alloc((size_t)NB * 8);  // 2MB zeroed
  size_t zbytes = off;                     // everything above must start zero
  unsigned long long* Epack = (unsigned long long*)alloc((size_t)NB * 8); // 2MB
  unsigned* seq   = (unsigned*)alloc((size_t)n * 4);               // 1MB
  uint2*    skey2 = (uint2*)alloc((size_t)n * 8);                  // 2MB
  unsigned* sidx  = (unsigned*)alloc((size_t)n * 4);               // 1MB
  float*    xh    = (float*)alloc((size_t)m * 4);
  if (off > ws_size) return;

  hipMemsetAsync(ws, 0, zbytes, stream);

  int gN = (n + BLK - 1) / BLK;              // 1024 for n=262144
  int tot = gN * BLK;
  int gS = NB / 1024;                        // 256 scan blocks
  k_hist<<<dim3(gN), dim3(BLK), 0, stream>>>(yt0, yp0, Hj, n, m, tot,
                                             rec, seq, bitmap);
  k_scan<<<dim3(gS), dim3(BLK), 0, stream>>>(rec, pub, Epack);
  k_scatter<<<dim3(gN), dim3(BLK), 0, stream>>>(yt0, yp0, n, seq, Epack,
                                                skey2, sidx);
  k_main<<<dim3(gN), dim3(BLK), 0, stream>>>(yp1, Hj, lv, n, m,
                                             bitmap, Epack, skey2, sidx,
                                             xh, accum, doneCnt,
                                             (float*)d_out);
}